// Round 13
// baseline (244.973 us; speedup 1.0000x reference)
//
#include <hip/hip_runtime.h>
#include <hip/hip_bf16.h>

#define DIMC 256
#define NB 4
#define NS 4096
#define KT 64               // keys per phase in attention
#define VS_ELEMS (KT * DIMC)   // 16384 ushorts per 32KB tile buffer

typedef __attribute__((ext_vector_type(4))) float f32x4;
typedef __attribute__((ext_vector_type(8))) short bf16x8;

__device__ __forceinline__ ushort f2bf(float f) {
  __hip_bfloat16 h = __float2bfloat16(f);
  return *reinterpret_cast<ushort*>(&h);
}
__device__ __forceinline__ float bf2f(ushort h) {
  uint u = ((uint)h) << 16;
  float f;
  __builtin_memcpy(&f, &u, 4);
  return f;
}

// async global->LDS DMA, 16B per lane; LDS dest = wave-uniform base + lane*16
__device__ __forceinline__ void gload16(const ushort* g, ushort* l) {
  __builtin_amdgcn_global_load_lds(
      (const __attribute__((address_space(1))) unsigned int*)g,
      (__attribute__((address_space(3))) unsigned int*)l,
      16, 0, 0);
}

// ---------------- prep: W hi/lo split + mask pack (one launch) ----------------
__global__ __launch_bounds__(256) void prep_kernel(
    const float* __restrict__ W, const int* __restrict__ mask,
    ushort* __restrict__ Whl, uint* __restrict__ pm32)
{
  if (blockIdx.x < 512) {
    const int col = blockIdx.x;          // 0..511
    const int k = threadIdx.x;           // 0..255
    const int srcrow = (col < 256) ? col : (col + 256);
    float f = W[(size_t)srcrow * 256 + k];
    ushort h = f2bf(f);
    Whl[(size_t)col * 256 + k] = h;
    Whl[131072 + (size_t)col * 256 + k] = f2bf(f - bf2f(h));
  } else {
    int t = (blockIdx.x - 512) * 256 + threadIdx.x;   // 0..511
    int b = t >> 7;
    int kt = (t >> 1) & 63;
    int kh = t & 1;
    const int* mrow = mask + b * NS + kt * 64 + kh * 32;
    uint wd = 0;
    for (int g = 0; g < 4; ++g)
      for (int ntl = 0; ntl < 2; ++ntl)
        for (int r = 0; r < 4; ++r)
          if (mrow[ntl * 16 + 4 * g + r] != 0) wd |= 1u << (8 * g + ntl * 4 + r);
    pm32[t] = wd;
  }
}

// ---------------- QV projection via MFMA (3-term bf16 compensation) ----------
// R8-validated 64-row version (grid 256).
__global__ __launch_bounds__(256) void qv_proj_kernel(
    const float* __restrict__ x, const ushort* __restrict__ Whl,
    const float* __restrict__ bias,
    ushort* __restrict__ qb, ushort* __restrict__ vb, ushort* __restrict__ vtb)
{
  const int tid  = threadIdx.x;
  const int w    = tid >> 6;
  const int lane = tid & 63;
  const int l15  = lane & 15;
  const int g    = (lane >> 4) & 3;
  const int r0   = blockIdx.x << 6;    // 64 rows
  const int colbase = w << 7;          // 128 cols per wave

  __shared__ ushort olds[64 * 520];    // output transpose staging (65KB)

  f32x4 acc[4][8];
  #pragma unroll
  for (int rt = 0; rt < 4; ++rt)
    #pragma unroll
    for (int ct = 0; ct < 8; ++ct) { acc[rt][ct].x=0.f; acc[rt][ct].y=0.f; acc[rt][ct].z=0.f; acc[rt][ct].w=0.f; }

  #pragma unroll 1
  for (int st = 0; st < 8; ++st) {
    bf16x8 xh[4], xl[4];
    #pragma unroll
    for (int rt = 0; rt < 4; ++rt) {
      const float* p = x + (size_t)(r0 + rt * 16 + l15) * DIMC + st * 32 + g * 8;
      float4 f0 = *(const float4*)p;
      float4 f1 = *(const float4*)(p + 4);
      union { bf16x8 v; ushort u[8]; } uh, ul;
      #pragma unroll
      for (int e = 0; e < 8; ++e) {
        float fe = (e < 4) ? ((const float*)&f0)[e] : ((const float*)&f1)[e - 4];
        ushort h = f2bf(fe);
        uh.u[e] = h;
        ul.u[e] = f2bf(fe - bf2f(h));
      }
      xh[rt] = uh.v;
      xl[rt] = ul.v;
    }
    #pragma unroll
    for (int ct = 0; ct < 8; ++ct) {
      const ushort* wp = Whl + (size_t)(colbase + ct * 16 + l15) * 256 + st * 32 + g * 8;
      bf16x8 wh = *(const bf16x8*)wp;
      bf16x8 wl = *(const bf16x8*)(wp + 131072);
      #pragma unroll
      for (int rt = 0; rt < 4; ++rt) {
        acc[rt][ct] = __builtin_amdgcn_mfma_f32_16x16x32_bf16(xh[rt], wh, acc[rt][ct], 0, 0, 0);
        acc[rt][ct] = __builtin_amdgcn_mfma_f32_16x16x32_bf16(xl[rt], wh, acc[rt][ct], 0, 0, 0);
        acc[rt][ct] = __builtin_amdgcn_mfma_f32_16x16x32_bf16(xh[rt], wl, acc[rt][ct], 0, 0, 0);
      }
    }
  }

  const float qscale = (colbase < 256) ? 0.0625f : 1.0f;
  #pragma unroll
  for (int ct = 0; ct < 8; ++ct) {
    const int col = colbase + ct * 16 + l15;
    const float bv = bias[(col < 256) ? col : (col + 256)];
    #pragma unroll
    for (int rt = 0; rt < 4; ++rt) {
      #pragma unroll
      for (int r = 0; r < 4; ++r)
        olds[(rt * 16 + 4 * g + r) * 520 + col] = f2bf((acc[rt][ct][r] + bv) * qscale);
    }
  }
  __syncthreads();

  #pragma unroll
  for (int i = 0; i < 16; ++i) {
    int task = tid + i * 256;
    int row = task >> 6, ch = task & 63;
    uint4 d = *(const uint4*)&olds[row * 520 + ch * 8];
    if (ch < 32) *(uint4*)&qb[(size_t)(r0 + row) * DIMC + ch * 8] = d;
    else         *(uint4*)&vb[(size_t)(r0 + row) * DIMC + (ch - 32) * 8] = d;
  }
  const int bbp = r0 >> 12;
  const int s0  = r0 & (NS - 1);
  const int vcol = tid;
  #pragma unroll
  for (int o = 0; o < 8; ++o) {
    union { uint4 v; ushort u[8]; } pk;
    #pragma unroll
    for (int j = 0; j < 8; ++j)
      pk.u[j] = olds[(o * 8 + j) * 520 + 256 + vcol];
    *(uint4*)&vtb[((size_t)(bbp * DIMC + vcol)) * NS + s0 + o * 8] = pk.v;
  }
}

// ---------------- flash attention: af from L2, vt via LDS, counted pipeline --
// Grid 256 = 128 q-blocks (128 rows) x 2 split-K halves. 8 waves = 4 pq x 2 kh.
// QK^T(t): af (V key-rows) loaded DIRECTLY from vb in L2 (64B-coalesced per
// 4-lane group) -> no vs LDS staging, no 4x pq duplication on the LDS pipe.
// PV(t-1): lagged, vf from vt LDS (staged by DMA, one phase ahead).
// Race-free by construction: phase t+1's af vmem-waits (afs older than its own
// DMAs) force-drain phase t's vt DMAs before PV reads them.
__global__ __launch_bounds__(512, 1) void attn_kernel(
    const ushort* __restrict__ qb, const ushort* __restrict__ vb,
    const ushort* __restrict__ vtb, const uint* __restrict__ pm32,
    float* __restrict__ outA, float* __restrict__ opB,
    float* __restrict__ mlA, float* __restrict__ mlB)
{
  const int tid  = threadIdx.x;
  const int w    = tid >> 6;
  const int lane = tid & 63;
  const int l15  = lane & 15;
  const int g    = (lane >> 4) & 3;
  const int kh   = w & 1;        // key half (QK^T) / d half (PV)
  const int pq   = w >> 1;       // 32-row q-subrange index

  const int s     = blockIdx.x & 1;          // split-K half
  const int qb128 = blockIdx.x >> 1;
  const int qrow0 = qb128 << 7;              // 128 q rows per block
  const int bb    = qrow0 >> 12;
  const int koff  = s << 11;                 // 2048-key offset

  float* opart = s ? opB : outA;
  float* mlp   = s ? mlB : mlA;

  extern __shared__ __align__(16) char smem[];
  uint*   pmlds = (uint*)smem;                        // 512 B
  ushort* vt0  = (ushort*)(smem + 1024);              // 32KB V^T 8-key chunks (swizzled)
  ushort* vt1  = vt0 + VS_ELEMS;                      // 32KB
  ushort* psb  = vt1 + VS_ELEMS;                      // 4 pq x 32 q x 72 = 18KB

  bf16x8 qreg[2][8];
  #pragma unroll
  for (int qt = 0; qt < 2; ++qt) {
    const int qrow = qrow0 + (pq << 5) + (qt << 4) + l15;
    #pragma unroll
    for (int st = 0; st < 8; ++st)
      qreg[qt][st] = *(const bf16x8*)&qb[(size_t)qrow * DIMC + ((st * 4 + g) << 3)];
  }

  if (tid < 128) pmlds[tid] = pm32[(bb << 7) + tid];

  auto stage_vt = [&](int kt, ushort* vtN) {
    #pragma unroll
    for (int i = 0; i < 4; ++i) {
      int d0 = i << 6;
      int dim = (d0 + lane) ^ ((w & 3) << 1);
      gload16(vtb + ((size_t)(bb * DIMC + dim)) * NS + koff + kt * KT + (w << 3),
              vtN + ((w << 8) + d0) * 8);
    }
  };

  __syncthreads();   // pmlds visible

  f32x4 acc_o[2][8];
  #pragma unroll
  for (int qt = 0; qt < 2; ++qt)
    #pragma unroll
    for (int nt = 0; nt < 8; ++nt) { acc_o[qt][nt].x=0.f; acc_o[qt][nt].y=0.f; acc_o[qt][nt].z=0.f; acc_o[qt][nt].w=0.f; }
  float l_s[2] = {0.f, 0.f};

  ushort* psw = psb + pq * (32 * 72);

  // af base: this wave's two key groups (kh*32 + {0,16} + l15)
  const int key0 = (kh << 5) + l15;

  #pragma unroll 1
  for (int t = 0; t < 32; ++t) {
    ushort* vtS = (t & 1) ? vt1 : vt0;     // stage vt(t)   (consumed next phase)
    ushort* vtP = (t & 1) ? vt0 : vt1;     // PV(t-1) source

    // ---- QK^T(t): af straight from L2 (vb), bf = qreg
    const ushort* vrow = vb + ((size_t)(bb * NS + koff + t * KT)) * DIMC;
    f32x4 sacc[2][2];
    #pragma unroll
    for (int qt = 0; qt < 2; ++qt) {
      sacc[qt][0].x=0.f; sacc[qt][0].y=0.f; sacc[qt][0].z=0.f; sacc[qt][0].w=0.f;
      sacc[qt][1] = sacc[qt][0];
    }
    __builtin_amdgcn_s_setprio(1);
    #pragma unroll
    for (int st = 0; st < 8; ++st) {
      bf16x8 af0 = *(const bf16x8*)&vrow[(size_t)key0 * DIMC + ((st * 4 + g) << 3)];
      bf16x8 af1 = *(const bf16x8*)&vrow[(size_t)(key0 + 16) * DIMC + ((st * 4 + g) << 3)];
      #pragma unroll
      for (int qt = 0; qt < 2; ++qt) {
        sacc[qt][0] = __builtin_amdgcn_mfma_f32_16x16x32_bf16(af0, qreg[qt][st], sacc[qt][0], 0, 0, 0);
        sacc[qt][1] = __builtin_amdgcn_mfma_f32_16x16x32_bf16(af1, qreg[qt][st], sacc[qt][1], 0, 0, 0);
      }
    }
    __builtin_amdgcn_s_setprio(0);

    // ---- stage vt(t) (DMAs newer than this phase's afs; left in flight at B)
    stage_vt(t, vtS);

    // ---- PV(t-1): our 128-d half x full 64 keys (vt(t-1) drained by af waits)
    if (t > 0) {
      bf16x8 pa[2][2];
      #pragma unroll
      for (int qt = 0; qt < 2; ++qt)
        #pragma unroll
        for (int ks2 = 0; ks2 < 2; ++ks2)
          pa[qt][ks2] = *(const bf16x8*)&psw[((qt << 4) + l15) * 72 + (ks2 << 5) + (g << 3)];
      __builtin_amdgcn_s_setprio(1);
      #pragma unroll
      for (int ntl = 0; ntl < 8; ++ntl) {
        const int d = ((kh << 3) + ntl) * 16 + l15;
        #pragma unroll
        for (int ks2 = 0; ks2 < 2; ++ks2) {
          const int kc = (ks2 << 2) + g;
          bf16x8 vf = *(const bf16x8*)&vtP[((kc << 8) + (d ^ ((kc & 3) << 1))) * 8];
          acc_o[0][ntl] = __builtin_amdgcn_mfma_f32_16x16x32_bf16(vf, pa[0][ks2], acc_o[0][ntl], 0, 0, 0);
          acc_o[1][ntl] = __builtin_amdgcn_mfma_f32_16x16x32_bf16(vf, pa[1][ks2], acc_o[1][ntl], 0, 0, 0);
        }
      }
      __builtin_amdgcn_s_setprio(0);
    }

    // ---- softmax(t)
    const int ktg = (s << 5) + t;
    uint mybits = (pmlds[(ktg << 1) + kh] >> (g << 3)) & 0xffu;
    float pv[2][8];
    #pragma unroll
    for (int qt = 0; qt < 2; ++qt) {
      #pragma unroll
      for (int ntl = 0; ntl < 2; ++ntl)
        #pragma unroll
        for (int r = 0; r < 4; ++r) {
          float vv = (mybits & (1u << (ntl * 4 + r))) ? sacc[qt][ntl][r] : -1e30f;
          pv[qt][ntl * 4 + r] = __expf(vv);
        }
      float rs = ((pv[qt][0] + pv[qt][1]) + (pv[qt][2] + pv[qt][3])) +
                 ((pv[qt][4] + pv[qt][5]) + (pv[qt][6] + pv[qt][7]));
      rs += __shfl_xor(rs, 16);
      rs += __shfl_xor(rs, 32);
      l_s[qt] += rs;
    }

    // ---- barrier A: all waves done reading ps(t-1)
    asm volatile("s_waitcnt lgkmcnt(0)" ::: "memory");
    __builtin_amdgcn_sched_barrier(0);
    __builtin_amdgcn_s_barrier();
    __builtin_amdgcn_sched_barrier(0);

    // ---- Pwrite(t)
    #pragma unroll
    for (int qt = 0; qt < 2; ++qt) {
      #pragma unroll
      for (int ntl = 0; ntl < 2; ++ntl) {
        uint2 pk;
        pk.x = (uint)f2bf(pv[qt][ntl*4+0]) | ((uint)f2bf(pv[qt][ntl*4+1]) << 16);
        pk.y = (uint)f2bf(pv[qt][ntl*4+2]) | ((uint)f2bf(pv[qt][ntl*4+3]) << 16);
        *(uint2*)&psw[((qt << 4) + l15) * 72 + (kh << 5) + ntl * 16 + 4 * g] = pk;
      }
    }

    // ---- barrier B: counted vmcnt (this phase's 4 vt DMAs stay in flight)
    asm volatile("s_waitcnt vmcnt(4) lgkmcnt(0)" ::: "memory");
    __builtin_amdgcn_sched_barrier(0);
    __builtin_amdgcn_s_barrier();
    __builtin_amdgcn_sched_barrier(0);
  }

  // ---- epilogue: drain vt(31) DMA, then PV(31)
  asm volatile("s_waitcnt vmcnt(0)" ::: "memory");
  __builtin_amdgcn_sched_barrier(0);
  __builtin_amdgcn_s_barrier();
  __builtin_amdgcn_sched_barrier(0);
  {
    ushort* vtP = vt1;   // t=31 staged into vt[31&1]=vt1
    bf16x8 pa[2][2];
    #pragma unroll
    for (int qt = 0; qt < 2; ++qt)
      #pragma unroll
      for (int ks2 = 0; ks2 < 2; ++ks2)
        pa[qt][ks2] = *(const bf16x8*)&psw[((qt << 4) + l15) * 72 + (ks2 << 5) + (g << 3)];
    __builtin_amdgcn_s_setprio(1);
    #pragma unroll
    for (int ntl = 0; ntl < 8; ++ntl) {
      const int d = ((kh << 3) + ntl) * 16 + l15;
      #pragma unroll
      for (int ks2 = 0; ks2 < 2; ++ks2) {
        const int kc = (ks2 << 2) + g;
        bf16x8 vf = *(const bf16x8*)&vtP[((kc << 8) + (d ^ ((kc & 3) << 1))) * 8];
        acc_o[0][ntl] = __builtin_amdgcn_mfma_f32_16x16x32_bf16(vf, pa[0][ks2], acc_o[0][ntl], 0, 0, 0);
        acc_o[1][ntl] = __builtin_amdgcn_mfma_f32_16x16x32_bf16(vf, pa[1][ks2], acc_o[1][ntl], 0, 0, 0);
      }
    }
    __builtin_amdgcn_s_setprio(0);
  }

  // ---- write unnormalized partial (our d-half) + per-half l
  #pragma unroll
  for (int qt = 0; qt < 2; ++qt) {
    const int qrow = qrow0 + (pq << 5) + (qt << 4) + l15;
    const size_t obase = (size_t)qrow * DIMC + 4 * g;
    #pragma unroll
    for (int ntl = 0; ntl < 8; ++ntl) {
      f32x4 o = acc_o[qt][ntl];
      *(float4*)&opart[obase + ((kh << 3) + ntl) * 16] = *(float4*)&o;
    }
    if (g == 0) mlp[(size_t)qrow * 2 + kh] = l_s[qt];
  }
}

// ---------------- split-K merge: out = (A + B) / (lA0+lA1+lB0+lB1) ----------
__global__ __launch_bounds__(256) void merge_kernel(
    float* __restrict__ outA, const float* __restrict__ opB,
    const float* __restrict__ mlA, const float* __restrict__ mlB)
{
  int id = blockIdx.x * 256 + threadIdx.x;   // 16384 rows x 64 float4
  int row = id >> 6;
  int c = (id & 63) << 2;
  float lT = (mlA[(size_t)row * 2] + mlA[(size_t)row * 2 + 1]) +
             (mlB[(size_t)row * 2] + mlB[(size_t)row * 2 + 1]);
  float inv = 1.f / lT;
  size_t o = (size_t)row * DIMC + c;
  float4 a = *(const float4*)&outA[o];
  float4 b = *(const float4*)&opB[o];
  float4 r;
  r.x = (a.x + b.x) * inv;
  r.y = (a.y + b.y) * inv;
  r.z = (a.z + b.z) * inv;
  r.w = (a.w + b.w) * inv;
  *(float4*)&outA[o] = r;
}

extern "C" void kernel_launch(void* const* d_in, const int* in_sizes, int n_in,
                              void* d_out, int out_size, void* d_ws, size_t ws_size,
                              hipStream_t stream) {
  const float* x    = (const float*)d_in[0];
  const float* W    = (const float*)d_in[1];
  const float* bias = (const float*)d_in[2];
  const int*   mask = (const int*)d_in[3];
  float* out = (float*)d_out;

  const size_t n = (size_t)NB * NS * DIMC;      // 4.19M elements
  ushort* qb  = (ushort*)d_ws;                  // 8.4 MB
  ushort* vb  = qb + n;                         // 8.4 MB
  ushort* vtb = vb + n;                         // 8.4 MB
  uint* pm32 = (uint*)(vtb + n);                // 2 KB
  ushort* Whl = (ushort*)(pm32 + 512);          // 512 KB
  float* opB = (float*)(Whl + 262144);          // 16.8 MB (s=1 partial)
  float* mlA = opB + n;                         // 128 KB
  float* mlB = mlA + 2 * (NB * NS);             // 128 KB

  prep_kernel<<<514, 256, 0, stream>>>(W, mask, Whl, pm32);
  qv_proj_kernel<<<(NB * NS) / 64, 256, 0, stream>>>(x, Whl, bias, qb, vb, vtb);

  const int smem_bytes = 1024 + 2 * VS_ELEMS * 2 + 4 * 32 * 72 * 2;  // ~83 KB
  attn_kernel<<<256, 512, smem_bytes, stream>>>(qb, vb, vtb, pm32, out, opB, mlA, mlB);
  merge_kernel<<<(NB * NS * DIMC / 4) / 256, 256, 0, stream>>>(out, opB, mlA, mlB);
}

// Round 14
// 147.336 us; speedup vs baseline: 1.6627x; 1.6627x over previous
//
#include <hip/hip_runtime.h>
#include <hip/hip_bf16.h>

#define DIMC 256
#define NB 4
#define NS 4096
#define KT 64               // keys per phase in attention
#define VS_ELEMS (KT * DIMC)   // 16384 ushorts per 32KB tile buffer

typedef __attribute__((ext_vector_type(4))) float f32x4;
typedef __attribute__((ext_vector_type(8))) short bf16x8;

__device__ __forceinline__ ushort f2bf(float f) {
  __hip_bfloat16 h = __float2bfloat16(f);
  return *reinterpret_cast<ushort*>(&h);
}
__device__ __forceinline__ float bf2f(ushort h) {
  uint u = ((uint)h) << 16;
  float f;
  __builtin_memcpy(&f, &u, 4);
  return f;
}

// async global->LDS DMA, 16B per lane; LDS dest = wave-uniform base + lane*16
__device__ __forceinline__ void gload16(const ushort* g, ushort* l) {
  __builtin_amdgcn_global_load_lds(
      (const __attribute__((address_space(1))) unsigned int*)g,
      (__attribute__((address_space(3))) unsigned int*)l,
      16, 0, 0);
}

// ------- prep: W hi/lo split + mask pack + x hi/lo split (one launch) --------
__global__ __launch_bounds__(256) void prep_kernel(
    const float* __restrict__ W, const int* __restrict__ mask,
    const float* __restrict__ x,
    ushort* __restrict__ Whl, uint* __restrict__ pm32,
    ushort* __restrict__ xhb, ushort* __restrict__ xlb)
{
  const int bid = blockIdx.x;
  if (bid < 512) {
    const int col = bid;                 // 0..511
    const int k = threadIdx.x;           // 0..255
    const int srcrow = (col < 256) ? col : (col + 256);
    float f = W[(size_t)srcrow * 256 + k];
    ushort h = f2bf(f);
    Whl[(size_t)col * 256 + k] = h;
    Whl[131072 + (size_t)col * 256 + k] = f2bf(f - bf2f(h));
  } else if (bid < 514) {
    int t = (bid - 512) * 256 + threadIdx.x;   // 0..511
    int b = t >> 7;
    int kt = (t >> 1) & 63;
    int kh = t & 1;
    const int* mrow = mask + b * NS + kt * 64 + kh * 32;
    uint wd = 0;
    for (int g = 0; g < 4; ++g)
      for (int ntl = 0; ntl < 2; ++ntl)
        for (int r = 0; r < 4; ++r)
          if (mrow[ntl * 16 + 4 * g + r] != 0) wd |= 1u << (8 * g + ntl * 4 + r);
    pm32[t] = wd;
  } else {
    // x hi/lo split: 2048 blocks x 256 threads x 8 elems
    size_t idx = ((size_t)(bid - 514) * 256 + threadIdx.x) * 8;
    float4 f0 = *(const float4*)&x[idx];
    float4 f1 = *(const float4*)&x[idx + 4];
    union { uint4 v; ushort u[8]; } ph, pl;
    #pragma unroll
    for (int e = 0; e < 8; ++e) {
      float fe = (e < 4) ? ((const float*)&f0)[e] : ((const float*)&f1)[e - 4];
      ushort h = f2bf(fe);
      ph.u[e] = h;
      pl.u[e] = f2bf(fe - bf2f(h));
    }
    *(uint4*)&xhb[idx] = ph.v;
    *(uint4*)&xlb[idx] = pl.v;
  }
}

// ---------------- QV projection via MFMA (3-term bf16 compensation) ----------
// 512 threads / 8 waves; wave w owns 64 rows x 64 cols; x pre-split to bf16.
__global__ __launch_bounds__(512) void qv_proj_kernel(
    const ushort* __restrict__ xhb, const ushort* __restrict__ xlb,
    const ushort* __restrict__ Whl, const float* __restrict__ bias,
    ushort* __restrict__ qb, ushort* __restrict__ vb, ushort* __restrict__ vtb)
{
  const int tid  = threadIdx.x;
  const int w    = tid >> 6;           // 0..7
  const int lane = tid & 63;
  const int l15  = lane & 15;
  const int g    = (lane >> 4) & 3;
  const int r0   = blockIdx.x << 6;    // 64 rows
  const int colbase = w << 6;          // 64 cols per wave

  __shared__ ushort olds[64 * 520];    // output transpose staging (66.5KB)

  f32x4 acc[4][4];
  #pragma unroll
  for (int rt = 0; rt < 4; ++rt)
    #pragma unroll
    for (int ct = 0; ct < 4; ++ct) { acc[rt][ct].x=0.f; acc[rt][ct].y=0.f; acc[rt][ct].z=0.f; acc[rt][ct].w=0.f; }

  #pragma unroll 1
  for (int st = 0; st < 8; ++st) {
    bf16x8 xh[4], xl[4];
    #pragma unroll
    for (int rt = 0; rt < 4; ++rt) {
      const size_t off = (size_t)(r0 + rt * 16 + l15) * DIMC + st * 32 + g * 8;
      xh[rt] = *(const bf16x8*)&xhb[off];
      xl[rt] = *(const bf16x8*)&xlb[off];
    }
    #pragma unroll
    for (int ct = 0; ct < 4; ++ct) {
      const ushort* wp = Whl + (size_t)(colbase + ct * 16 + l15) * 256 + st * 32 + g * 8;
      bf16x8 wh = *(const bf16x8*)wp;
      bf16x8 wl = *(const bf16x8*)(wp + 131072);
      #pragma unroll
      for (int rt = 0; rt < 4; ++rt) {
        acc[rt][ct] = __builtin_amdgcn_mfma_f32_16x16x32_bf16(xh[rt], wh, acc[rt][ct], 0, 0, 0);
        acc[rt][ct] = __builtin_amdgcn_mfma_f32_16x16x32_bf16(xl[rt], wh, acc[rt][ct], 0, 0, 0);
        acc[rt][ct] = __builtin_amdgcn_mfma_f32_16x16x32_bf16(xh[rt], wl, acc[rt][ct], 0, 0, 0);
      }
    }
  }

  const float qscale = (colbase < 256) ? 0.0625f : 1.0f;
  #pragma unroll
  for (int ct = 0; ct < 4; ++ct) {
    const int col = colbase + ct * 16 + l15;
    const float bv = bias[(col < 256) ? col : (col + 256)];
    #pragma unroll
    for (int rt = 0; rt < 4; ++rt) {
      #pragma unroll
      for (int r = 0; r < 4; ++r)
        olds[(rt * 16 + 4 * g + r) * 520 + col] = f2bf((acc[rt][ct][r] + bv) * qscale);
    }
  }
  __syncthreads();

  // qb / vb coalesced stores: 64 rows x 64 chunks = 4096 tasks / 512 threads
  #pragma unroll
  for (int i = 0; i < 8; ++i) {
    int task = tid + i * 512;
    int row = task >> 6, ch = task & 63;
    uint4 d = *(const uint4*)&olds[row * 520 + ch * 8];
    if (ch < 32) *(uint4*)&qb[(size_t)(r0 + row) * DIMC + ch * 8] = d;
    else         *(uint4*)&vb[(size_t)(r0 + row) * DIMC + (ch - 32) * 8] = d;
  }
  // vtb stores: 256 cols x 8 o-iters, split across 512 threads
  const int bbp = r0 >> 12;
  const int s0  = r0 & (NS - 1);
  const int vcol = tid & 255;
  const int ohalf = (tid >> 8) * 4;
  #pragma unroll
  for (int oo = 0; oo < 4; ++oo) {
    int o = ohalf + oo;
    union { uint4 v; ushort u[8]; } pk;
    #pragma unroll
    for (int j = 0; j < 8; ++j)
      pk.u[j] = olds[(o * 8 + j) * 520 + 256 + vcol];
    *(uint4*)&vtb[((size_t)(bbp * DIMC + vcol)) * NS + s0 + o * 8] = pk.v;
  }
}

// ---------------- flash attention (R8-exact): split-K, no-max softmax --------
__global__ __launch_bounds__(512, 1) void attn_kernel(
    const ushort* __restrict__ qb, const ushort* __restrict__ vb,
    const ushort* __restrict__ vtb, const uint* __restrict__ pm32,
    float* __restrict__ outA, float* __restrict__ opB,
    float* __restrict__ mlA, float* __restrict__ mlB)
{
  const int tid  = threadIdx.x;
  const int w    = tid >> 6;
  const int lane = tid & 63;
  const int l15  = lane & 15;
  const int g    = (lane >> 4) & 3;
  const int kh   = w & 1;        // key half (QK^T) / d half (PV)
  const int pq   = w >> 1;       // 32-row q-subrange index

  const int s     = blockIdx.x & 1;          // split-K half
  const int qb128 = blockIdx.x >> 1;
  const int qrow0 = qb128 << 7;              // 128 q rows per block
  const int bb    = qrow0 >> 12;
  const int koff  = s << 11;                 // 2048-key offset

  float* opart = s ? opB : outA;
  float* mlp   = s ? mlB : mlA;

  extern __shared__ __align__(16) char smem[];
  uint*   pmlds = (uint*)smem;                        // 512 B
  ushort* vs0  = (ushort*)(smem + 1024);              // 32KB key-major V (swizzled)
  ushort* vs1  = vs0 + VS_ELEMS;
  ushort* vt0  = vs1 + VS_ELEMS;                      // 32KB V^T 8-key chunks (swizzled)
  ushort* vt1  = vt0 + VS_ELEMS;
  ushort* psb  = vt1 + VS_ELEMS;                      // 4 pq x 32 q x 72 = 18KB

  bf16x8 qreg[2][8];
  #pragma unroll
  for (int qt = 0; qt < 2; ++qt) {
    const int qrow = qrow0 + (pq << 5) + (qt << 4) + l15;
    #pragma unroll
    for (int st = 0; st < 8; ++st)
      qreg[qt][st] = *(const bf16x8*)&qb[(size_t)qrow * DIMC + ((st * 4 + g) << 3)];
  }

  if (tid < 128) pmlds[tid] = pm32[(bb << 7) + tid];

  auto stage_vs = [&](int kt, ushort* vsN) {
    const ushort* vbase = vb + ((size_t)(bb * NS + koff + kt * KT)) * DIMC;
    #pragma unroll
    for (int i = 0; i < 4; ++i) {
      int rr0 = (w << 3) + (i << 1);
      int row = rr0 + (lane >> 5);
      int cs  = lane & 31;
      gload16(vbase + row * DIMC + ((cs ^ (row & 7)) << 3), vsN + (rr0 << 8));
    }
  };
  auto stage_vt = [&](int kt, ushort* vtN) {
    #pragma unroll
    for (int i = 0; i < 4; ++i) {
      int d0 = i << 6;
      int dim = (d0 + lane) ^ ((w & 3) << 1);
      gload16(vtb + ((size_t)(bb * DIMC + dim)) * NS + koff + kt * KT + (w << 3),
              vtN + ((w << 8) + d0) * 8);
    }
  };

  stage_vs(0, vs0);
  __syncthreads();   // drains prologue DMA + pmlds (one-time)

  f32x4 acc_o[2][8];
  #pragma unroll
  for (int qt = 0; qt < 2; ++qt)
    #pragma unroll
    for (int nt = 0; nt < 8; ++nt) { acc_o[qt][nt].x=0.f; acc_o[qt][nt].y=0.f; acc_o[qt][nt].z=0.f; acc_o[qt][nt].w=0.f; }
  float l_s[2] = {0.f, 0.f};

  ushort* psw = psb + pq * (32 * 72);

  #pragma unroll 1
  for (int t = 0; t < 32; ++t) {
    ushort* vsQ = (t & 1) ? vs1 : vs0;     // QK(t) source
    ushort* vsS = (t & 1) ? vs0 : vs1;     // stage vs(t+1)
    ushort* vtS = (t & 1) ? vt1 : vt0;     // stage vt(t)   (consumed next phase)
    ushort* vtP = (t & 1) ? vt0 : vt1;     // PV(t-1) source

    if (t + 1 < 32) stage_vs(t + 1, vsS);
    stage_vt(t, vtS);

    // ---- QK^T(t)
    f32x4 sacc[2][2];
    #pragma unroll
    for (int qt = 0; qt < 2; ++qt) {
      sacc[qt][0].x=0.f; sacc[qt][0].y=0.f; sacc[qt][0].z=0.f; sacc[qt][0].w=0.f;
      sacc[qt][1] = sacc[qt][0];
    }
    __builtin_amdgcn_s_setprio(1);
    #pragma unroll
    for (int st = 0; st < 8; ++st) {
      const int key0 = (kh << 5) + l15;
      bf16x8 af0 = *(const bf16x8*)&vsQ[(key0 * 32 + ((st * 4 + g) ^ (key0 & 7))) * 8];
      const int key1 = key0 + 16;
      bf16x8 af1 = *(const bf16x8*)&vsQ[(key1 * 32 + ((st * 4 + g) ^ (key1 & 7))) * 8];
      #pragma unroll
      for (int qt = 0; qt < 2; ++qt) {
        sacc[qt][0] = __builtin_amdgcn_mfma_f32_16x16x32_bf16(af0, qreg[qt][st], sacc[qt][0], 0, 0, 0);
        sacc[qt][1] = __builtin_amdgcn_mfma_f32_16x16x32_bf16(af1, qreg[qt][st], sacc[qt][1], 0, 0, 0);
      }
    }
    __builtin_amdgcn_s_setprio(0);

    // ---- PV(t-1)
    if (t > 0) {
      bf16x8 pa[2][2];
      #pragma unroll
      for (int qt = 0; qt < 2; ++qt)
        #pragma unroll
        for (int ks2 = 0; ks2 < 2; ++ks2)
          pa[qt][ks2] = *(const bf16x8*)&psw[((qt << 4) + l15) * 72 + (ks2 << 5) + (g << 3)];
      __builtin_amdgcn_s_setprio(1);
      #pragma unroll
      for (int ntl = 0; ntl < 8; ++ntl) {
        const int d = ((kh << 3) + ntl) * 16 + l15;
        #pragma unroll
        for (int ks2 = 0; ks2 < 2; ++ks2) {
          const int kc = (ks2 << 2) + g;
          bf16x8 vf = *(const bf16x8*)&vtP[((kc << 8) + (d ^ ((kc & 3) << 1))) * 8];
          acc_o[0][ntl] = __builtin_amdgcn_mfma_f32_16x16x32_bf16(vf, pa[0][ks2], acc_o[0][ntl], 0, 0, 0);
          acc_o[1][ntl] = __builtin_amdgcn_mfma_f32_16x16x32_bf16(vf, pa[1][ks2], acc_o[1][ntl], 0, 0, 0);
        }
      }
      __builtin_amdgcn_s_setprio(0);
    }

    // ---- softmax(t)
    const int ktg = (s << 5) + t;
    uint mybits = (pmlds[(ktg << 1) + kh] >> (g << 3)) & 0xffu;
    float pv[2][8];
    #pragma unroll
    for (int qt = 0; qt < 2; ++qt) {
      #pragma unroll
      for (int ntl = 0; ntl < 2; ++ntl)
        #pragma unroll
        for (int r = 0; r < 4; ++r) {
          float vv = (mybits & (1u << (ntl * 4 + r))) ? sacc[qt][ntl][r] : -1e30f;
          pv[qt][ntl * 4 + r] = __expf(vv);
        }
      float rs = ((pv[qt][0] + pv[qt][1]) + (pv[qt][2] + pv[qt][3])) +
                 ((pv[qt][4] + pv[qt][5]) + (pv[qt][6] + pv[qt][7]));
      rs += __shfl_xor(rs, 16);
      rs += __shfl_xor(rs, 32);
      l_s[qt] += rs;
    }

    // ---- barrier A: all waves done reading ps(t-1)
    asm volatile("s_waitcnt lgkmcnt(0)" ::: "memory");
    __builtin_amdgcn_sched_barrier(0);
    __builtin_amdgcn_s_barrier();
    __builtin_amdgcn_sched_barrier(0);

    // ---- Pwrite(t)
    #pragma unroll
    for (int qt = 0; qt < 2; ++qt) {
      #pragma unroll
      for (int ntl = 0; ntl < 2; ++ntl) {
        uint2 pk;
        pk.x = (uint)f2bf(pv[qt][ntl*4+0]) | ((uint)f2bf(pv[qt][ntl*4+1]) << 16);
        pk.y = (uint)f2bf(pv[qt][ntl*4+2]) | ((uint)f2bf(pv[qt][ntl*4+3]) << 16);
        *(uint2*)&psw[((qt << 4) + l15) * 72 + (kh << 5) + ntl * 16 + 4 * g] = pk;
      }
    }

    // ---- barrier B: counted vmcnt + ps visible
    if (t + 1 < 32)
      asm volatile("s_waitcnt vmcnt(8) lgkmcnt(0)" ::: "memory");
    else
      asm volatile("s_waitcnt vmcnt(4) lgkmcnt(0)" ::: "memory");
    __builtin_amdgcn_sched_barrier(0);
    __builtin_amdgcn_s_barrier();
    __builtin_amdgcn_sched_barrier(0);
  }

  // ---- epilogue: drain vt(31) DMA, then PV(31)
  asm volatile("s_waitcnt vmcnt(0)" ::: "memory");
  __builtin_amdgcn_sched_barrier(0);
  __builtin_amdgcn_s_barrier();
  __builtin_amdgcn_sched_barrier(0);
  {
    ushort* vtP = vt1;   // t=31: vt[31&1]
    bf16x8 pa[2][2];
    #pragma unroll
    for (int qt = 0; qt < 2; ++qt)
      #pragma unroll
      for (int ks2 = 0; ks2 < 2; ++ks2)
        pa[qt][ks2] = *(const bf16x8*)&psw[((qt << 4) + l15) * 72 + (ks2 << 5) + (g << 3)];
    __builtin_amdgcn_s_setprio(1);
    #pragma unroll
    for (int ntl = 0; ntl < 8; ++ntl) {
      const int d = ((kh << 3) + ntl) * 16 + l15;
      #pragma unroll
      for (int ks2 = 0; ks2 < 2; ++ks2) {
        const int kc = (ks2 << 2) + g;
        bf16x8 vf = *(const bf16x8*)&vtP[((kc << 8) + (d ^ ((kc & 3) << 1))) * 8];
        acc_o[0][ntl] = __builtin_amdgcn_mfma_f32_16x16x32_bf16(vf, pa[0][ks2], acc_o[0][ntl], 0, 0, 0);
        acc_o[1][ntl] = __builtin_amdgcn_mfma_f32_16x16x32_bf16(vf, pa[1][ks2], acc_o[1][ntl], 0, 0, 0);
      }
    }
    __builtin_amdgcn_s_setprio(0);
  }

  // ---- write unnormalized partial (our d-half) + per-half l
  #pragma unroll
  for (int qt = 0; qt < 2; ++qt) {
    const int qrow = qrow0 + (pq << 5) + (qt << 4) + l15;
    const size_t obase = (size_t)qrow * DIMC + 4 * g;
    #pragma unroll
    for (int ntl = 0; ntl < 8; ++ntl) {
      f32x4 o = acc_o[qt][ntl];
      *(float4*)&opart[obase + ((kh << 3) + ntl) * 16] = *(float4*)&o;
    }
    if (g == 0) mlp[(size_t)qrow * 2 + kh] = l_s[qt];
  }
}

// ---------------- split-K merge: out = (A + B) / (lA0+lA1+lB0+lB1) ----------
__global__ __launch_bounds__(256) void merge_kernel(
    float* __restrict__ outA, const float* __restrict__ opB,
    const float* __restrict__ mlA, const float* __restrict__ mlB)
{
  int id = blockIdx.x * 256 + threadIdx.x;   // 16384 rows x 64 float4
  int row = id >> 6;
  int c = (id & 63) << 2;
  float lT = (mlA[(size_t)row * 2] + mlA[(size_t)row * 2 + 1]) +
             (mlB[(size_t)row * 2] + mlB[(size_t)row * 2 + 1]);
  float inv = 1.f / lT;
  size_t o = (size_t)row * DIMC + c;
  float4 a = *(const float4*)&outA[o];
  float4 b = *(const float4*)&opB[o];
  float4 r;
  r.x = (a.x + b.x) * inv;
  r.y = (a.y + b.y) * inv;
  r.z = (a.z + b.z) * inv;
  r.w = (a.w + b.w) * inv;
  *(float4*)&outA[o] = r;
}

extern "C" void kernel_launch(void* const* d_in, const int* in_sizes, int n_in,
                              void* d_out, int out_size, void* d_ws, size_t ws_size,
                              hipStream_t stream) {
  const float* x    = (const float*)d_in[0];
  const float* W    = (const float*)d_in[1];
  const float* bias = (const float*)d_in[2];
  const int*   mask = (const int*)d_in[3];
  float* out = (float*)d_out;

  const size_t n = (size_t)NB * NS * DIMC;      // 4.19M elements
  ushort* qb  = (ushort*)d_ws;                  // 8.4 MB
  ushort* vb  = qb + n;                         // 8.4 MB
  ushort* vtb = vb + n;                         // 8.4 MB
  uint* pm32 = (uint*)(vtb + n);                // 2 KB
  ushort* Whl = (ushort*)(pm32 + 512);          // 512 KB
  float* opB = (float*)(Whl + 262144);          // 16.8 MB (s=1 partial)
  float* mlA = opB + n;                         // 128 KB
  float* mlB = mlA + 2 * (NB * NS);             // 128 KB
  // xh/xl alias opB (used only before attn overwrites it)
  ushort* xhb = (ushort*)opB;                   // 8.4 MB
  ushort* xlb = xhb + n;                        // 8.4 MB

  prep_kernel<<<2562, 256, 0, stream>>>(W, mask, x, Whl, pm32, xhb, xlb);
  qv_proj_kernel<<<(NB * NS) / 64, 512, 0, stream>>>(xhb, xlb, Whl, bias, qb, vb, vtb);

  const int smem_bytes = 1024 + 4 * VS_ELEMS * 2 + 4 * 32 * 72 * 2;  // 147 KB
  attn_kernel<<<256, 512, smem_bytes, stream>>>(qb, vb, vtb, pm32, out, opB, mlA, mlB);
  merge_kernel<<<(NB * NS * DIMC / 4) / 256, 256, 0, stream>>>(out, opB, mlA, mlB);
}